// Round 17
// baseline (45.973 us; speedup 1.0000x reference)
//
#include <hip/hip_runtime.h>
#include <hip/hip_bf16.h>
#include <stdint.h>

#define B_ 16
#define Q_ 1800
#define C_ 256
#define WPR 29            // u64 words per adjacency row = ceil(1800/64)
#define QPAD 1856         // padded compacted-row capacity
#define TBK 15            // 128-wide tiles per dim
#define NTRI 120          // triangular tile count = TBK*(TBK+1)/2
#define OUT_SIG_ELEMS (B_*Q_*C_)
#define NBPB 58           // prepsel blocks per batch (32 rows each; 58*32=1856)

typedef unsigned long long u64;
typedef unsigned int u32;
typedef __attribute__((ext_vector_type(8))) short bf16x8;   // 8 bf16 (4 VGPRs)
typedef __attribute__((ext_vector_type(4))) float f32x4;    // 4 fp32 acc

// ---------------- K1 (path A): fused select + prep + SPECULATIVE gather ----
// 58 blocks/batch; each redundantly runs the CHEAP sign-test selection scan
// (selected <=> logit>=0.0f <=> sigmoid>=0.5; no expf) then handles 32 rows:
// speculative output copy (clean-case answer), normalize->bf16 nsig, rowmin
// init, and its slice of sel_idx. expf only on live rows + rare empty path.
__global__ __launch_bounds__(256)
void k_prepsel(const float* __restrict__ sig, const float* __restrict__ logits,
               int* __restrict__ sel_idx, int* __restrict__ sel_cnt,
               int* __restrict__ dirty,
               unsigned short* __restrict__ nsig, u32* __restrict__ rowmin,
               float* __restrict__ out_sig, float* __restrict__ out_mask,
               float* __restrict__ out_scores) {
  const int b = blockIdx.y, g = blockIdx.x;       // g in [0, NBPB)
  const int t = threadIdx.x, lane = t & 63, wid = t >> 6;
  const int p0 = g * 32;
  __shared__ int wsum[4];
  __shared__ u64 kw[4];
  __shared__ int s_tot;
  __shared__ int slot[32];

  const float* lgb = logits + b * Q_;
  int f[8]; int cnt = 0;
  #pragma unroll
  for (int e = 0; e < 8; ++e) {
    int q = t * 8 + e; int fl = 0;
    if (q < Q_) fl = (lgb[q] >= 0.0f) ? 1 : 0;    // == (sigmoid >= 0.5)
    f[e] = fl; cnt += fl;
  }
  int incl = cnt;
  #pragma unroll
  for (int d = 1; d < 64; d <<= 1) {
    int v = __shfl_up(incl, d, 64);
    if (lane >= d) incl += v;
  }
  if (lane == 63) wsum[wid] = incl;
  __syncthreads();
  if (t == 0) {
    int acc = 0;
    #pragma unroll
    for (int i = 0; i < 4; ++i) { int v = wsum[i]; wsum[i] = acc; acc += v; }
    s_tot = acc;
  }
  __syncthreads();
  int excl0 = wsum[wid] + incl - cnt;
  int S = s_tot;
  int fbq = -1;
  if (S == 0) {                     // rare fallback: true score-ordered argmax
    u64 mk = 0;
    for (int q = t; q < Q_; q += 256) {
      float sc = 1.0f / (1.0f + expf(-lgb[q]));
      u64 key = ((u64)__float_as_uint(sc) << 32) | (u32)(~(u32)q); // max sc, min idx
      mk = (mk > key) ? mk : key;
    }
    #pragma unroll
    for (int d = 1; d < 64; d <<= 1) { u64 o = __shfl_xor(mk, d, 64); mk = (o > mk) ? o : mk; }
    if (lane == 0) kw[wid] = mk;
    __syncthreads();
    u64 m2 = kw[0];
    #pragma unroll
    for (int i = 1; i < 4; ++i) m2 = (kw[i] > m2) ? kw[i] : m2;
    fbq = (int)(~(u32)m2);
    S = 1;
  }
  if (g == 0 && t == 0) { sel_cnt[b] = S; dirty[b] = 0; }

  if (t < 32) slot[t] = -1;
  __syncthreads();
  if (fbq >= 0) {
    if (g == 0 && t == 0) { slot[0] = fbq; sel_idx[b * Q_] = fbq; }
  } else {
    int ex = excl0;
    #pragma unroll
    for (int e = 0; e < 8; ++e) {
      if (f[e]) {
        int q = t * 8 + e;
        if (ex >= p0 && ex < p0 + 32) {           // this block's slice only
          slot[ex - p0] = q;
          sel_idx[b * Q_ + ex] = q;
        }
        ex++;
      }
    }
  }
  __syncthreads();

  const int Spad   = (S + 63) & ~63;              // rowmin coverage
  const int Spad128 = (S + 127) & ~127;           // nsig zero coverage (tile edge)

  #pragma unroll
  for (int r = 0; r < 8; ++r) {
    int i = wid * 8 + r;
    int p = p0 + i;                               // p < QPAD by construction
    if (p < Spad && lane == 0) rowmin[b * QPAD + p] = 0xFFFFFFFFu;
    if (p < S) {
      int row = slot[i];
      const float* src = sig + ((size_t)b * Q_ + row) * C_;
      float4 v = *reinterpret_cast<const float4*>(src + lane * 4);

      float* orow = out_sig + ((size_t)b * Q_ + p) * C_;    // speculative out
      *reinterpret_cast<float4*>(orow + lane * 4) = v;
      if (lane == 0) {
        out_mask[b * Q_ + p] = 1.0f;
        out_scores[b * Q_ + p] = 1.0f / (1.0f + expf(-lgb[row]));
      }

      float ss = v.x * v.x + v.y * v.y + v.z * v.z + v.w * v.w;
      #pragma unroll
      for (int m = 32; m; m >>= 1) ss += __shfl_xor(ss, m, 64);
      float inv = 1.0f / fmaxf(sqrtf(ss), 1e-12f);
      __hip_bfloat16 h0 = __float2bfloat16(v.x * inv);
      __hip_bfloat16 h1 = __float2bfloat16(v.y * inv);
      __hip_bfloat16 h2 = __float2bfloat16(v.z * inv);
      __hip_bfloat16 h3 = __float2bfloat16(v.w * inv);
      unsigned short u0, u1, u2, u3;
      __builtin_memcpy(&u0, &h0, 2); __builtin_memcpy(&u1, &h1, 2);
      __builtin_memcpy(&u2, &h2, 2); __builtin_memcpy(&u3, &h3, 2);
      uint2 wv;
      wv.x = (u32)u0 | ((u32)u1 << 16);
      wv.y = (u32)u2 | ((u32)u3 << 16);
      *reinterpret_cast<uint2*>(nsig + ((size_t)b * QPAD + p) * C_ + lane * 4) = wv;
    } else {
      if (p < Spad128)                            // zero-pad to tile edge
        *reinterpret_cast<uint2*>(nsig + ((size_t)b * QPAD + p) * C_ + lane * 4) =
            make_uint2(0u, 0u);
      if (p < Q_) {                               // zero output row
        float* orow = out_sig + ((size_t)b * Q_ + p) * C_;
        *reinterpret_cast<float4*>(orow + lane * 4) = make_float4(0.f, 0.f, 0.f, 0.f);
        if (lane == 0) {
          out_mask[b * Q_ + p] = 0.0f;
          out_scores[b * Q_ + p] = 0.0f;
        }
      }
    }
  }
}

// ---------------- K2: LDS-staged MFMA cosine-sim, triangular ---------------
// r16-verified body + staging row-guard (rows >= QPAD read as zero; only
// reachable when S > 1728).
__global__ __launch_bounds__(256)
void k_sim(const unsigned short* __restrict__ nsig, const int* __restrict__ sel_cnt,
           u64* __restrict__ adj, u32* __restrict__ rowmin,
           int* __restrict__ dirty) {
  int lin = blockIdx.x;
  int b = lin & 15;
  int u = lin >> 4, tib = 0;
  while (u >= TBK - tib) { u -= TBK - tib; ++tib; }
  int tjb = tib + u;                          // tib <= tjb < TBK
  int S = sel_cnt[b];
  if (tjb * 128 >= S) return;                 // implies tib*128 < S
  const bool diag = (tib == tjb);

  __shared__ uint4 Alds[2048];
  __shared__ uint4 Blds[2048];
  __shared__ u64 adjtile[4][64];

  const int t = threadIdx.x;
  const int wv = t >> 6, lane = t & 63;
  const int lr = lane & 15, lg = lane >> 4;

  const int i1 = tib * 128 + (wv >> 1) * 64;
  const int j1 = tjb * 128 + (wv & 1) * 64;
  const bool live = (i1 < S) && (j1 < S);

  const char* gbase = (const char*)(nsig + (size_t)b * QPAD * C_);
  const char* arow = gbase + (size_t)tib * 128 * 512;
  const char* brow = gbase + (size_t)tjb * 128 * 512;

  f32x4 acc[4][4];
  #pragma unroll
  for (int rs = 0; rs < 4; ++rs)
    #pragma unroll
    for (int cg = 0; cg < 4; ++cg) acc[rs][cg] = (f32x4){0.f, 0.f, 0.f, 0.f};

  const int ra0 = (wv >> 1) * 64;
  const int rb0 = (wv & 1) * 64;
  const char* Bbase = reinterpret_cast<const char*>(diag ? Alds : Blds);

  for (int kh = 0; kh < 2; ++kh) {
    #pragma unroll
    for (int it = 0; it < 8; ++it) {
      int o = it * 4096 + t * 16;
      int r = o >> 8;
      int w = o & 255;
      int sw = o ^ ((r & 7) << 4);            // swizzled LDS byte offset
      uint4 zz = make_uint4(0u, 0u, 0u, 0u);
      uint4 va = (tib * 128 + r < QPAD)
          ? *reinterpret_cast<const uint4*>(arow + (size_t)r * 512 + kh * 256 + w) : zz;
      Alds[sw >> 4] = va;
      if (!diag) {
        uint4 vb = (tjb * 128 + r < QPAD)
            ? *reinterpret_cast<const uint4*>(brow + (size_t)r * 512 + kh * 256 + w) : zz;
        Blds[sw >> 4] = vb;
      }
    }
    __syncthreads();
    if (live) {
      #pragma unroll
      for (int ks = 0; ks < 4; ++ks) {
        bf16x8 af[4], bf[4];
        #pragma unroll
        for (int rs = 0; rs < 4; ++rs) {
          int r = ra0 + rs * 16 + lr;
          int byte = r * 256 + ((ks * 64 + lg * 16) ^ ((r & 7) << 4));
          af[rs] = *reinterpret_cast<const bf16x8*>(
              reinterpret_cast<const char*>(Alds) + byte);
        }
        #pragma unroll
        for (int cg = 0; cg < 4; ++cg) {
          int r = rb0 + cg * 16 + lr;
          int byte = r * 256 + ((ks * 64 + lg * 16) ^ ((r & 7) << 4));
          bf[cg] = *reinterpret_cast<const bf16x8*>(Bbase + byte);
        }
        #pragma unroll
        for (int rs = 0; rs < 4; ++rs)
          #pragma unroll
          for (int cg = 0; cg < 4; ++cg)
            acc[rs][cg] = __builtin_amdgcn_mfma_f32_16x16x32_bf16(
                af[rs], bf[cg], acc[rs][cg], 0, 0, 0);
      }
    }
    __syncthreads();
  }

  if (!live) return;
  adjtile[wv][lane] = 0ull;                   // wave-private strip
  #pragma unroll
  for (int rs = 0; rs < 4; ++rs) {
    #pragma unroll
    for (int j = 0; j < 4; ++j) {
      u64 bits = 0ull;
      if (acc[rs][0][j] >= 0.8f) bits |= 1ull << (0  + lr);
      if (acc[rs][1][j] >= 0.8f) bits |= 1ull << (16 + lr);
      if (acc[rs][2][j] >= 0.8f) bits |= 1ull << (32 + lr);
      if (acc[rs][3][j] >= 0.8f) bits |= 1ull << (48 + lr);
      if (bits) atomicOr(&adjtile[wv][rs * 16 + lg * 4 + j], bits);
    }
  }
  int gi = i1 + lane;
  u64 word = adjtile[wv][lane];
  u64 selfbit = (i1 == j1) ? (1ull << lane) : 0ull;
  bool offd = (gi < S) && ((word & ~selfbit) != 0ull);
  if (__any(offd) && lane == 0) atomicOr(&dirty[b], 1);
  if (gi < S) {
    adj[((size_t)b * Q_ + gi) * WPR + (j1 >> 6)] = word;
    if (word) atomicMin(&rowmin[b * QPAD + gi], (u32)(j1 + __builtin_ctzll(word)));
  }
  if (!diag) {                                // mirrored word via bit-transpose
    u64 tw = 0ull;
    for (int i = 0; i < 64; ++i)
      tw |= ((adjtile[wv][i] >> lane) & 1ull) << i;
    int gj = j1 + lane;
    if (gj < S) {
      adj[((size_t)b * Q_ + gj) * WPR + (i1 >> 6)] = tw;
      if (tw) atomicMin(&rowmin[b * QPAD + gj], (u32)(i1 + __builtin_ctzll(tw)));
    }
  }
}

// ---------------- K3: fix — exits instantly when clean (r16 verbatim) ------
__global__ __launch_bounds__(1024)
void k_fix(const float* __restrict__ sig, const float* __restrict__ logits,
           const int* __restrict__ sel_idx, const int* __restrict__ sel_cnt,
           const u64* __restrict__ adj, const u32* __restrict__ rowmin,
           const int* __restrict__ dirty,
           int* __restrict__ best_idx, float* __restrict__ best_sc,
           float* __restrict__ out_sig, float* __restrict__ out_mask,
           float* __restrict__ out_scores) {
  int b = blockIdx.x;
  if (!dirty[b]) return;                      // clean: ~free
  int t = threadIdx.x;
  int lane = t & 63, wid = t >> 6;
  __shared__ int lab[Q_];
  __shared__ int lab2[Q_];
  __shared__ u64 best[Q_];
  __shared__ int wsum[16];
  __shared__ int s_tot;
  __shared__ int s_changed;

  int S = sel_cnt[b];
  int nw = (S + 63) >> 6;
  const u64* arow0 = adj + (size_t)b * Q_ * WPR;

  for (int s = t; s < S; s += 1024) {
    u32 m = rowmin[b * QPAD + s];
    lab[s] = (int)(((u32)s < m) ? (u32)s : m);
  }
  __syncthreads();
  for (int iter = 0; iter < Q_ + 2; ++iter) {
    if (t == 0) s_changed = 0;
    __syncthreads();
    for (int s = t; s < S; s += 1024) {
      int m = lab[s];
      const u64* row = arow0 + (size_t)s * WPR;
      for (int w = 0; w < nw; ++w) {
        u64 msk = row[w];
        while (msk) {
          int j = (w << 6) + __builtin_ctzll(msk);
          int lj = lab[j];
          m = (lj < m) ? lj : m;
          msk &= msk - 1;
        }
      }
      lab2[s] = m;
      if (m != lab[s]) s_changed = 1;
    }
    __syncthreads();
    int ch = s_changed;
    for (int s = t; s < S; s += 1024) lab[s] = lab2[s];
    __syncthreads();
    if (!ch) break;
  }

  for (int s = t; s < S; s += 1024) best[s] = 0ull;
  __syncthreads();
  const int* sidx = sel_idx + b * Q_;
  for (int s = t; s < S; s += 1024) {
    int orig = sidx[s];
    float sc = 1.0f / (1.0f + expf(-logits[b * Q_ + orig]));
    u64 key = ((u64)__float_as_uint(sc) << 32) | (u32)(~(u32)orig);
    atomicMax(&best[lab[s]], key);
  }
  __syncthreads();

  int f[2]; int cnt = 0;
  #pragma unroll
  for (int e = 0; e < 2; ++e) {
    int s = t * 2 + e;
    int fl = (s < S && lab[s] == s) ? 1 : 0;
    f[e] = fl; cnt += fl;
  }
  int incl = cnt;
  #pragma unroll
  for (int d = 1; d < 64; d <<= 1) {
    int v = __shfl_up(incl, d, 64);
    if (lane >= d) incl += v;
  }
  if (lane == 63) wsum[wid] = incl;
  __syncthreads();
  if (t == 0) {
    int acc = 0;
    #pragma unroll
    for (int i = 0; i < 16; ++i) { int v = wsum[i]; wsum[i] = acc; acc += v; }
    s_tot = acc;
  }
  __syncthreads();
  int excl = wsum[wid] + incl - cnt;
  #pragma unroll
  for (int e = 0; e < 2; ++e) {
    if (f[e]) {
      int s = t * 2 + e;
      u64 key = best[s];
      best_idx[b * Q_ + excl] = (int)(~(u32)key);
      best_sc[b * Q_ + excl] = __uint_as_float((u32)(key >> 32));
      excl++;
    }
  }
  __syncthreads();
  int n = s_tot;

  for (int p = wid; p < Q_; p += 16) {
    float* orow = out_sig + ((size_t)b * Q_ + p) * C_;
    if (p < n) {
      int row = best_idx[b * Q_ + p];
      float4 v = *reinterpret_cast<const float4*>(sig + ((size_t)b * Q_ + row) * C_ + lane * 4);
      *reinterpret_cast<float4*>(orow + lane * 4) = v;
      if (lane == 0) {
        out_mask[b * Q_ + p] = 1.0f;
        out_scores[b * Q_ + p] = best_sc[b * Q_ + p];
      }
    } else {
      *reinterpret_cast<float4*>(orow + lane * 4) = make_float4(0.f, 0.f, 0.f, 0.f);
      if (lane == 0) {
        out_mask[b * Q_ + p] = 0.0f;
        out_scores[b * Q_ + p] = 0.0f;
      }
    }
  }
}

// ---------------- Fallback kernels (r15/r16 verbatim; small-ws paths) ------
__global__ __launch_bounds__(256)
void k_compact(const float* __restrict__ logits,
               int* __restrict__ sel_idx, int* __restrict__ sel_cnt,
               int* __restrict__ dirty) {
  int b = blockIdx.x, t = threadIdx.x;
  int lane = t & 63, wid = t >> 6;
  __shared__ int wsum[4];
  __shared__ int s_tot;
  __shared__ u64 kw[4];
  const float* lgb = logits + b * Q_;
  if (t == 0) dirty[b] = 0;

  int f[8]; int cnt = 0;
  #pragma unroll
  for (int e = 0; e < 8; ++e) {
    int q = t * 8 + e; int fl = 0;
    if (q < Q_) fl = (lgb[q] >= 0.0f) ? 1 : 0;
    f[e] = fl; cnt += fl;
  }
  int incl = cnt;
  #pragma unroll
  for (int d = 1; d < 64; d <<= 1) {
    int v = __shfl_up(incl, d, 64);
    if (lane >= d) incl += v;
  }
  if (lane == 63) wsum[wid] = incl;
  __syncthreads();
  if (t == 0) {
    int acc = 0;
    #pragma unroll
    for (int i = 0; i < 4; ++i) { int v = wsum[i]; wsum[i] = acc; acc += v; }
    s_tot = acc;
  }
  __syncthreads();
  int excl = wsum[wid] + incl - cnt;
  int total = s_tot;

  if (total > 0) {
    #pragma unroll
    for (int e = 0; e < 8; ++e) {
      if (f[e]) { sel_idx[b * Q_ + excl] = t * 8 + e; excl++; }
    }
    if (t == 0) sel_cnt[b] = total;
  } else {
    u64 mk = 0;
    for (int q = t; q < Q_; q += 256) {
      float sc = 1.0f / (1.0f + expf(-lgb[q]));
      u64 key = ((u64)__float_as_uint(sc) << 32) | (u32)(~(u32)q);
      mk = (mk > key) ? mk : key;
    }
    #pragma unroll
    for (int d = 1; d < 64; d <<= 1) { u64 o = __shfl_xor(mk, d, 64); mk = (o > mk) ? o : mk; }
    if (lane == 0) kw[wid] = mk;
    __syncthreads();
    if (t == 0) {
      u64 m2 = kw[0];
      #pragma unroll
      for (int i = 1; i < 4; ++i) m2 = (kw[i] > m2) ? kw[i] : m2;
      sel_idx[b * Q_] = (int)(~(u32)m2);
      sel_cnt[b] = 1;
    }
  }
}

__global__ __launch_bounds__(256)
void k_prep(const float* __restrict__ sig, const int* __restrict__ sel_idx,
            const int* __restrict__ sel_cnt, unsigned short* __restrict__ nsig,
            u32* __restrict__ rowmin) {
  int b = blockIdx.y;
  int p = blockIdx.x * 4 + (threadIdx.x >> 6);
  int lane = threadIdx.x & 63;
  int S = sel_cnt[b];
  int Spad = (S + 63) & ~63;
  int Spad128 = (S + 127) & ~127;
  if (p >= Spad128 || p >= QPAD) {
    if (p < Spad && lane == 0) rowmin[b * QPAD + p] = 0xFFFFFFFFu;
    return;
  }
  if (p < Spad && lane == 0) rowmin[b * QPAD + p] = 0xFFFFFFFFu;
  unsigned short* dst = nsig + ((size_t)b * QPAD + p) * C_;
  if (p >= S) {
    *reinterpret_cast<uint2*>(dst + lane * 4) = make_uint2(0u, 0u);
    return;
  }
  int row = sel_idx[b * Q_ + p];
  const float* src = sig + ((size_t)b * Q_ + row) * C_;
  float4 v = *reinterpret_cast<const float4*>(src + lane * 4);
  float ss = v.x * v.x + v.y * v.y + v.z * v.z + v.w * v.w;
  #pragma unroll
  for (int m = 32; m; m >>= 1) ss += __shfl_xor(ss, m, 64);
  float inv = 1.0f / fmaxf(sqrtf(ss), 1e-12f);
  __hip_bfloat16 h0 = __float2bfloat16(v.x * inv);
  __hip_bfloat16 h1 = __float2bfloat16(v.y * inv);
  __hip_bfloat16 h2 = __float2bfloat16(v.z * inv);
  __hip_bfloat16 h3 = __float2bfloat16(v.w * inv);
  unsigned short u0, u1, u2, u3;
  __builtin_memcpy(&u0, &h0, 2); __builtin_memcpy(&u1, &h1, 2);
  __builtin_memcpy(&u2, &h2, 2); __builtin_memcpy(&u3, &h3, 2);
  uint2 wv;
  wv.x = (u32)u0 | ((u32)u1 << 16);
  wv.y = (u32)u2 | ((u32)u3 << 16);
  *reinterpret_cast<uint2*>(dst + lane * 4) = wv;
}

__global__ __launch_bounds__(256)
void k_ccgather(const float* __restrict__ sig, const float* __restrict__ logits,
                const int* __restrict__ sel_idx, const int* __restrict__ sel_cnt,
                const u64* __restrict__ adj, const u32* __restrict__ rowmin,
                float* __restrict__ out_sig, float* __restrict__ out_mask,
                float* __restrict__ out_scores) {
  const int b = blockIdx.y, g = blockIdx.x;
  const int t = threadIdx.x, lane = t & 63, wid = t >> 6;
  __shared__ int lab[Q_];
  __shared__ int lab2[Q_];
  __shared__ u64 best[Q_];
  __shared__ int wsum[4];
  __shared__ int s_tot;
  __shared__ int s_dirty;

  const int S = sel_cnt[b];
  if (t == 0) s_dirty = 0;
  __syncthreads();
  for (int s = t; s < S; s += 256)
    if (rowmin[b * QPAD + s] != (u32)s) s_dirty = 1;
  __syncthreads();

  const int p = g * 4 + wid;
  float* orow = out_sig + ((size_t)b * Q_ + p) * C_;

  if (!s_dirty) {
    if (p < S) {
      int row = sel_idx[b * Q_ + p];
      float4 v = *reinterpret_cast<const float4*>(sig + ((size_t)b * Q_ + row) * C_ + lane * 4);
      *reinterpret_cast<float4*>(orow + lane * 4) = v;
      if (lane == 0) {
        out_mask[b * Q_ + p] = 1.0f;
        out_scores[b * Q_ + p] = 1.0f / (1.0f + expf(-logits[b * Q_ + row]));
      }
    } else {
      *reinterpret_cast<float4*>(orow + lane * 4) = make_float4(0.f, 0.f, 0.f, 0.f);
      if (lane == 0) {
        out_mask[b * Q_ + p] = 0.0f;
        out_scores[b * Q_ + p] = 0.0f;
      }
    }
    return;
  }

  const int nw = (S + 63) >> 6;
  const u64* arow0 = adj + (size_t)b * Q_ * WPR;
  __shared__ int s_chg;

  if (t == 0) s_chg = 1;
  for (int s = t; s < S; s += 256) {
    u32 m = rowmin[b * QPAD + s];
    lab[s] = (int)(((u32)s < m) ? (u32)s : m);
  }
  __syncthreads();
  for (int iter = 0; iter < Q_ + 2; ++iter) {
    if (t == 0) s_chg = 0;
    __syncthreads();
    for (int s = t; s < S; s += 256) {
      int m = lab[s];
      const u64* row = arow0 + (size_t)s * WPR;
      for (int w = 0; w < nw; ++w) {
        u64 msk = row[w];
        while (msk) {
          int j = (w << 6) + __builtin_ctzll(msk);
          int lj = lab[j];
          m = (lj < m) ? lj : m;
          msk &= msk - 1;
        }
      }
      lab2[s] = m;
      if (m != lab[s]) s_chg = 1;
    }
    __syncthreads();
    int ch = s_chg;
    for (int s = t; s < S; s += 256) lab[s] = lab2[s];
    __syncthreads();
    if (!ch) break;
  }

  for (int s = t; s < S; s += 256) best[s] = 0ull;
  __syncthreads();
  const int* sidx = sel_idx + b * Q_;
  for (int s = t; s < S; s += 256) {
    int orig = sidx[s];
    float sc = 1.0f / (1.0f + expf(-logits[b * Q_ + orig]));
    u64 key = ((u64)__float_as_uint(sc) << 32) | (u32)(~(u32)orig);
    atomicMax(&best[lab[s]], key);
  }
  __syncthreads();

  __shared__ int slot[4];
  int rf[8]; int rcnt = 0;
  #pragma unroll
  for (int e = 0; e < 8; ++e) {
    int s = t * 8 + e;
    int fl = (s < S && lab[s] == s) ? 1 : 0;
    rf[e] = fl; rcnt += fl;
  }
  int rincl = rcnt;
  #pragma unroll
  for (int d = 1; d < 64; d <<= 1) {
    int v = __shfl_up(rincl, d, 64);
    if (lane >= d) rincl += v;
  }
  if (t < 4) slot[t] = -1;
  if (lane == 63) wsum[wid] = rincl;
  __syncthreads();
  if (t == 0) {
    int acc = 0;
    #pragma unroll
    for (int i = 0; i < 4; ++i) { int v = wsum[i]; wsum[i] = acc; acc += v; }
    s_tot = acc;
  }
  __syncthreads();
  int rex = wsum[wid] + rincl - rcnt;
  #pragma unroll
  for (int e = 0; e < 8; ++e) {
    if (rf[e]) {
      if (rex >= g * 4 && rex < g * 4 + 4) slot[rex - g * 4] = t * 8 + e;
      rex++;
    }
  }
  __syncthreads();
  int n = s_tot;

  if (p < n) {
    u64 key = best[slot[wid]];
    int orig = (int)(~(u32)key);
    float4 v = *reinterpret_cast<const float4*>(sig + ((size_t)b * Q_ + orig) * C_ + lane * 4);
    *reinterpret_cast<float4*>(orow + lane * 4) = v;
    if (lane == 0) {
      out_mask[b * Q_ + p] = 1.0f;
      out_scores[b * Q_ + p] = __uint_as_float((u32)(key >> 32));
    }
  } else {
    *reinterpret_cast<float4*>(orow + lane * 4) = make_float4(0.f, 0.f, 0.f, 0.f);
    if (lane == 0) {
      out_mask[b * Q_ + p] = 0.0f;
      out_scores[b * Q_ + p] = 0.0f;
    }
  }
}

extern "C" void kernel_launch(void* const* d_in, const int* in_sizes, int n_in,
                              void* d_out, int out_size, void* d_ws, size_t ws_size,
                              hipStream_t stream) {
  const float* p0 = (const float*)d_in[0];
  const float* p1 = (const float*)d_in[1];
  const float* sig;  const float* logits;
  if (in_sizes[0] == B_ * Q_ * C_) { sig = p0; logits = p1; }
  else                             { sig = p1; logits = p0; }

  float* out = (float*)d_out;
  float* out_mask   = out + OUT_SIG_ELEMS;
  float* out_scores = out + OUT_SIG_ELEMS + B_ * Q_;

  char* w = (char*)d_ws;
  int* sel_cnt = (int*)w;  w += 256;
  int* dirty   = (int*)w;  w += 256;
  int* sel_idx = (int*)w;  w += B_ * Q_ * 4;

  dim3 gg(Q_ / 4, B_);

  // Path A needs all scratch in ws (outputs written early):
  const size_t need_A = 512 + 3 * (size_t)B_ * Q_ * 4 + (size_t)B_ * QPAD * 4 +
                        (size_t)B_ * Q_ * WPR * 8 + (size_t)B_ * QPAD * C_ * 2;
  // Path B: nsig in d_out scratch, outputs last:
  const size_t need_B = 512 + (size_t)B_ * Q_ * 4 + (size_t)B_ * QPAD * 4 +
                        (size_t)B_ * Q_ * WPR * 8;

  if (ws_size >= need_A) {
    int* best_idx  = (int*)w;   w += B_ * Q_ * 4;
    float* best_sc = (float*)w; w += B_ * Q_ * 4;
    u32* rowmin = (u32*)w;      w += (size_t)B_ * QPAD * 4;
    u64* adj    = (u64*)w;      w += (size_t)B_ * Q_ * WPR * 8;
    unsigned short* nsig = (unsigned short*)w;

    dim3 gps(NBPB, B_);
    k_prepsel<<<gps, 256, 0, stream>>>(sig, logits, sel_idx, sel_cnt, dirty,
                                       nsig, rowmin, out, out_mask, out_scores);
    k_sim<<<B_ * NTRI, 256, 0, stream>>>(nsig, sel_cnt, adj, rowmin, dirty);
    k_fix<<<B_, 1024, 0, stream>>>(sig, logits, sel_idx, sel_cnt, adj, rowmin,
                                   dirty, best_idx, best_sc,
                                   out, out_mask, out_scores);
  } else if (ws_size >= need_B) {
    u32* rowmin = (u32*)w;  w += (size_t)B_ * QPAD * 4;
    u64* adj    = (u64*)w;
    unsigned short* nsig = (unsigned short*)((char*)d_out + (size_t)(8u << 20));
    dim3 gp(QPAD / 4, B_);

    k_compact<<<B_, 256, 0, stream>>>(logits, sel_idx, sel_cnt, dirty);
    k_prep<<<gp, 256, 0, stream>>>(sig, sel_idx, sel_cnt, nsig, rowmin);
    k_sim<<<B_ * NTRI, 256, 0, stream>>>(nsig, sel_cnt, adj, rowmin, dirty);
    k_ccgather<<<gg, 256, 0, stream>>>(sig, logits, sel_idx, sel_cnt, adj, rowmin,
                                       out, out_mask, out_scores);
  } else {
    // minimal-ws: adj in d_out (dirty-path reads only), rowmin in ws (fits).
    u64* adj    = (u64*)d_out;
    u32* rowmin = (u32*)w;
    unsigned short* nsig = (unsigned short*)((char*)d_out + (size_t)(8u << 20));
    dim3 gp(QPAD / 4, B_);

    k_compact<<<B_, 256, 0, stream>>>(logits, sel_idx, sel_cnt, dirty);
    k_prep<<<gp, 256, 0, stream>>>(sig, sel_idx, sel_cnt, nsig, rowmin);
    k_sim<<<B_ * NTRI, 256, 0, stream>>>(nsig, sel_cnt, adj, rowmin, dirty);
    k_ccgather<<<gg, 256, 0, stream>>>(sig, logits, sel_idx, sel_cnt, adj, rowmin,
                                       out, out_mask, out_scores);
  }
}

// Round 18
// 44.057 us; speedup vs baseline: 1.0435x; 1.0435x over previous
//
#include <hip/hip_runtime.h>
#include <hip/hip_bf16.h>
#include <stdint.h>

#define B_ 16
#define Q_ 1800
#define C_ 256
#define WPR 29            // u64 words per adjacency row = ceil(1800/64)
#define QPAD 1856         // padded compacted-row capacity
#define TBK 15            // 128-wide tiles per dim
#define NTRI 120          // triangular tile count = TBK*(TBK+1)/2
#define OUT_SIG_ELEMS (B_*Q_*C_)

typedef unsigned long long u64;
typedef unsigned int u32;
typedef __attribute__((ext_vector_type(8))) short bf16x8;   // 8 bf16 (4 VGPRs)
typedef __attribute__((ext_vector_type(4))) float f32x4;    // 4 fp32 acc

// ---------------- K1: selection + compaction (16 blocks; sign-test) --------
// selected <=> sigmoid(x)>=0.5 <=> x>=0.0f. expf only on the rare empty path.
// Also zeroes the per-batch dirty flag.
__global__ __launch_bounds__(256)
void k_compact(const float* __restrict__ logits,
               int* __restrict__ sel_idx, int* __restrict__ sel_cnt,
               int* __restrict__ dirty) {
  int b = blockIdx.x, t = threadIdx.x;
  int lane = t & 63, wid = t >> 6;
  __shared__ int wsum[4];
  __shared__ int s_tot;
  __shared__ u64 kw[4];
  const float* lgb = logits + b * Q_;
  if (t == 0) dirty[b] = 0;

  int f[8]; int cnt = 0;
  #pragma unroll
  for (int e = 0; e < 8; ++e) {
    int q = t * 8 + e; int fl = 0;
    if (q < Q_) fl = (lgb[q] >= 0.0f) ? 1 : 0;   // == (sigmoid >= 0.5)
    f[e] = fl; cnt += fl;
  }
  int incl = cnt;
  #pragma unroll
  for (int d = 1; d < 64; d <<= 1) {
    int v = __shfl_up(incl, d, 64);
    if (lane >= d) incl += v;
  }
  if (lane == 63) wsum[wid] = incl;
  __syncthreads();
  if (t == 0) {
    int acc = 0;
    #pragma unroll
    for (int i = 0; i < 4; ++i) { int v = wsum[i]; wsum[i] = acc; acc += v; }
    s_tot = acc;
  }
  __syncthreads();
  int excl = wsum[wid] + incl - cnt;
  int total = s_tot;

  if (total > 0) {
    #pragma unroll
    for (int e = 0; e < 8; ++e) {
      if (f[e]) { sel_idx[b * Q_ + excl] = t * 8 + e; excl++; }
    }
    if (t == 0) sel_cnt[b] = total;
  } else {                        // rare fallback: true score-ordered argmax
    u64 mk = 0;
    for (int q = t; q < Q_; q += 256) {
      float sc = 1.0f / (1.0f + expf(-lgb[q]));
      u64 key = ((u64)__float_as_uint(sc) << 32) | (u32)(~(u32)q); // max sc, min idx
      mk = (mk > key) ? mk : key;
    }
    #pragma unroll
    for (int d = 1; d < 64; d <<= 1) { u64 o = __shfl_xor(mk, d, 64); mk = (o > mk) ? o : mk; }
    if (lane == 0) kw[wid] = mk;
    __syncthreads();
    if (t == 0) {
      u64 m2 = kw[0];
      #pragma unroll
      for (int i = 1; i < 4; ++i) m2 = (kw[i] > m2) ? kw[i] : m2;
      sel_idx[b * Q_] = (int)(~(u32)m2);
      sel_cnt[b] = 1;
    }
  }
}

// ---------------- K2 (big-ws): prep + SPECULATIVE gather -------------------
// One read of sig row feeds BOTH the raw speculative output row (clean-case
// answer: all components singletons) and the normalized bf16 nsig row.
// nsig zero-padded to the 128-tile edge (Spad128). No LDS, no barriers.
// k_fix later overwrites outputs only if dirty.
__global__ __launch_bounds__(256)
void k_prepg(const float* __restrict__ sig, const float* __restrict__ logits,
             const int* __restrict__ sel_idx, const int* __restrict__ sel_cnt,
             unsigned short* __restrict__ nsig, u32* __restrict__ rowmin,
             float* __restrict__ out_sig, float* __restrict__ out_mask,
             float* __restrict__ out_scores) {
  int b = blockIdx.y;
  int p = blockIdx.x * 4 + (threadIdx.x >> 6);
  int lane = threadIdx.x & 63;
  int S = sel_cnt[b];
  int Spad = (S + 63) & ~63;
  int Spad128 = (S + 127) & ~127;

  if (p < Spad && lane == 0) rowmin[b * QPAD + p] = 0xFFFFFFFFu;

  if (p < S) {
    int row = sel_idx[b * Q_ + p];
    const float* src = sig + ((size_t)b * Q_ + row) * C_;
    float4 v = *reinterpret_cast<const float4*>(src + lane * 4);

    float* orow = out_sig + ((size_t)b * Q_ + p) * C_;      // speculative out
    *reinterpret_cast<float4*>(orow + lane * 4) = v;
    if (lane == 0) {
      out_mask[b * Q_ + p] = 1.0f;
      out_scores[b * Q_ + p] = 1.0f / (1.0f + expf(-logits[b * Q_ + row]));
    }

    float ss = v.x * v.x + v.y * v.y + v.z * v.z + v.w * v.w;
    #pragma unroll
    for (int m = 32; m; m >>= 1) ss += __shfl_xor(ss, m, 64);
    float inv = 1.0f / fmaxf(sqrtf(ss), 1e-12f);
    __hip_bfloat16 h0 = __float2bfloat16(v.x * inv);
    __hip_bfloat16 h1 = __float2bfloat16(v.y * inv);
    __hip_bfloat16 h2 = __float2bfloat16(v.z * inv);
    __hip_bfloat16 h3 = __float2bfloat16(v.w * inv);
    unsigned short u0, u1, u2, u3;
    __builtin_memcpy(&u0, &h0, 2); __builtin_memcpy(&u1, &h1, 2);
    __builtin_memcpy(&u2, &h2, 2); __builtin_memcpy(&u3, &h3, 2);
    uint2 wv;
    wv.x = (u32)u0 | ((u32)u1 << 16);
    wv.y = (u32)u2 | ((u32)u3 << 16);
    *reinterpret_cast<uint2*>(nsig + ((size_t)b * QPAD + p) * C_ + lane * 4) = wv;
  } else {
    if (p < Spad128 && p < QPAD)                             // zero to tile edge
      *reinterpret_cast<uint2*>(nsig + ((size_t)b * QPAD + p) * C_ + lane * 4) =
          make_uint2(0u, 0u);
    if (p < Q_) {                                            // zero out row
      float* orow = out_sig + ((size_t)b * Q_ + p) * C_;
      *reinterpret_cast<float4*>(orow + lane * 4) = make_float4(0.f, 0.f, 0.f, 0.f);
      if (lane == 0) {
        out_mask[b * Q_ + p] = 0.0f;
        out_scores[b * Q_ + p] = 0.0f;
      }
    }
  }
}

// ---------------- K3: LDS-staged MFMA cosine-sim, triangular ---------------
// r16-verified body + staging row-guard (rows >= QPAD read as zero; only
// reachable when S > 1728). Per-batch dirty flag from primary words.
__global__ __launch_bounds__(256)
void k_sim(const unsigned short* __restrict__ nsig, const int* __restrict__ sel_cnt,
           u64* __restrict__ adj, u32* __restrict__ rowmin,
           int* __restrict__ dirty) {
  int lin = blockIdx.x;
  int b = lin & 15;
  int u = lin >> 4, tib = 0;
  while (u >= TBK - tib) { u -= TBK - tib; ++tib; }
  int tjb = tib + u;                          // tib <= tjb < TBK
  int S = sel_cnt[b];
  if (tjb * 128 >= S) return;                 // implies tib*128 < S
  const bool diag = (tib == tjb);

  __shared__ uint4 Alds[2048];
  __shared__ uint4 Blds[2048];
  __shared__ u64 adjtile[4][64];

  const int t = threadIdx.x;
  const int wv = t >> 6, lane = t & 63;
  const int lr = lane & 15, lg = lane >> 4;

  const int i1 = tib * 128 + (wv >> 1) * 64;
  const int j1 = tjb * 128 + (wv & 1) * 64;
  const bool live = (i1 < S) && (j1 < S);

  const char* gbase = (const char*)(nsig + (size_t)b * QPAD * C_);
  const char* arow = gbase + (size_t)tib * 128 * 512;
  const char* brow = gbase + (size_t)tjb * 128 * 512;

  f32x4 acc[4][4];
  #pragma unroll
  for (int rs = 0; rs < 4; ++rs)
    #pragma unroll
    for (int cg = 0; cg < 4; ++cg) acc[rs][cg] = (f32x4){0.f, 0.f, 0.f, 0.f};

  const int ra0 = (wv >> 1) * 64;
  const int rb0 = (wv & 1) * 64;
  const char* Bbase = reinterpret_cast<const char*>(diag ? Alds : Blds);

  for (int kh = 0; kh < 2; ++kh) {
    #pragma unroll
    for (int it = 0; it < 8; ++it) {
      int o = it * 4096 + t * 16;
      int r = o >> 8;
      int w = o & 255;
      int sw = o ^ ((r & 7) << 4);            // swizzled LDS byte offset
      uint4 zz = make_uint4(0u, 0u, 0u, 0u);
      uint4 va = (tib * 128 + r < QPAD)
          ? *reinterpret_cast<const uint4*>(arow + (size_t)r * 512 + kh * 256 + w) : zz;
      Alds[sw >> 4] = va;
      if (!diag) {
        uint4 vb = (tjb * 128 + r < QPAD)
            ? *reinterpret_cast<const uint4*>(brow + (size_t)r * 512 + kh * 256 + w) : zz;
        Blds[sw >> 4] = vb;
      }
    }
    __syncthreads();
    if (live) {
      #pragma unroll
      for (int ks = 0; ks < 4; ++ks) {
        bf16x8 af[4], bf[4];
        #pragma unroll
        for (int rs = 0; rs < 4; ++rs) {
          int r = ra0 + rs * 16 + lr;
          int byte = r * 256 + ((ks * 64 + lg * 16) ^ ((r & 7) << 4));
          af[rs] = *reinterpret_cast<const bf16x8*>(
              reinterpret_cast<const char*>(Alds) + byte);
        }
        #pragma unroll
        for (int cg = 0; cg < 4; ++cg) {
          int r = rb0 + cg * 16 + lr;
          int byte = r * 256 + ((ks * 64 + lg * 16) ^ ((r & 7) << 4));
          bf[cg] = *reinterpret_cast<const bf16x8*>(Bbase + byte);
        }
        #pragma unroll
        for (int rs = 0; rs < 4; ++rs)
          #pragma unroll
          for (int cg = 0; cg < 4; ++cg)
            acc[rs][cg] = __builtin_amdgcn_mfma_f32_16x16x32_bf16(
                af[rs], bf[cg], acc[rs][cg], 0, 0, 0);
      }
    }
    __syncthreads();
  }

  if (!live) return;
  adjtile[wv][lane] = 0ull;                   // wave-private strip
  #pragma unroll
  for (int rs = 0; rs < 4; ++rs) {
    #pragma unroll
    for (int j = 0; j < 4; ++j) {
      u64 bits = 0ull;
      if (acc[rs][0][j] >= 0.8f) bits |= 1ull << (0  + lr);
      if (acc[rs][1][j] >= 0.8f) bits |= 1ull << (16 + lr);
      if (acc[rs][2][j] >= 0.8f) bits |= 1ull << (32 + lr);
      if (acc[rs][3][j] >= 0.8f) bits |= 1ull << (48 + lr);
      if (bits) atomicOr(&adjtile[wv][rs * 16 + lg * 4 + j], bits);
    }
  }
  int gi = i1 + lane;
  u64 word = adjtile[wv][lane];
  u64 selfbit = (i1 == j1) ? (1ull << lane) : 0ull;
  bool offd = (gi < S) && ((word & ~selfbit) != 0ull);
  if (__any(offd) && lane == 0) atomicOr(&dirty[b], 1);
  if (gi < S) {
    adj[((size_t)b * Q_ + gi) * WPR + (j1 >> 6)] = word;
    if (word) atomicMin(&rowmin[b * QPAD + gi], (u32)(j1 + __builtin_ctzll(word)));
  }
  if (!diag) {                                // mirrored word via bit-transpose
    u64 tw = 0ull;
    for (int i = 0; i < 64; ++i)
      tw |= ((adjtile[wv][i] >> lane) & 1ull) << i;
    int gj = j1 + lane;
    if (gj < S) {
      adj[((size_t)b * Q_ + gj) * WPR + (i1 >> 6)] = tw;
      if (tw) atomicMin(&rowmin[b * QPAD + gj], (u32)(i1 + __builtin_ctzll(tw)));
    }
  }
}

// ---------------- K4: fix — exits instantly when clean ---------------------
// Dirty batch (rare): full r9-verified CC + rewrite of that batch's outputs.
__global__ __launch_bounds__(1024)
void k_fix(const float* __restrict__ sig, const float* __restrict__ logits,
           const int* __restrict__ sel_idx, const int* __restrict__ sel_cnt,
           const u64* __restrict__ adj, const u32* __restrict__ rowmin,
           const int* __restrict__ dirty,
           int* __restrict__ best_idx, float* __restrict__ best_sc,
           float* __restrict__ out_sig, float* __restrict__ out_mask,
           float* __restrict__ out_scores) {
  int b = blockIdx.x;
  if (!dirty[b]) return;                      // clean: ~free
  int t = threadIdx.x;
  int lane = t & 63, wid = t >> 6;
  __shared__ int lab[Q_];
  __shared__ int lab2[Q_];
  __shared__ u64 best[Q_];
  __shared__ int wsum[16];
  __shared__ int s_tot;
  __shared__ int s_changed;

  int S = sel_cnt[b];
  int nw = (S + 63) >> 6;
  const u64* arow0 = adj + (size_t)b * Q_ * WPR;

  for (int s = t; s < S; s += 1024) {
    u32 m = rowmin[b * QPAD + s];
    lab[s] = (int)(((u32)s < m) ? (u32)s : m);
  }
  __syncthreads();
  for (int iter = 0; iter < Q_ + 2; ++iter) {
    if (t == 0) s_changed = 0;
    __syncthreads();
    for (int s = t; s < S; s += 1024) {
      int m = lab[s];
      const u64* row = arow0 + (size_t)s * WPR;
      for (int w = 0; w < nw; ++w) {
        u64 msk = row[w];
        while (msk) {
          int j = (w << 6) + __builtin_ctzll(msk);
          int lj = lab[j];
          m = (lj < m) ? lj : m;
          msk &= msk - 1;
        }
      }
      lab2[s] = m;
      if (m != lab[s]) s_changed = 1;
    }
    __syncthreads();
    int ch = s_changed;
    for (int s = t; s < S; s += 1024) lab[s] = lab2[s];
    __syncthreads();
    if (!ch) break;
  }

  for (int s = t; s < S; s += 1024) best[s] = 0ull;
  __syncthreads();
  const int* sidx = sel_idx + b * Q_;
  for (int s = t; s < S; s += 1024) {
    int orig = sidx[s];
    float sc = 1.0f / (1.0f + expf(-logits[b * Q_ + orig]));
    u64 key = ((u64)__float_as_uint(sc) << 32) | (u32)(~(u32)orig);
    atomicMax(&best[lab[s]], key);
  }
  __syncthreads();

  int f[2]; int cnt = 0;
  #pragma unroll
  for (int e = 0; e < 2; ++e) {
    int s = t * 2 + e;
    int fl = (s < S && lab[s] == s) ? 1 : 0;
    f[e] = fl; cnt += fl;
  }
  int incl = cnt;
  #pragma unroll
  for (int d = 1; d < 64; d <<= 1) {
    int v = __shfl_up(incl, d, 64);
    if (lane >= d) incl += v;
  }
  if (lane == 63) wsum[wid] = incl;
  __syncthreads();
  if (t == 0) {
    int acc = 0;
    #pragma unroll
    for (int i = 0; i < 16; ++i) { int v = wsum[i]; wsum[i] = acc; acc += v; }
    s_tot = acc;
  }
  __syncthreads();
  int excl = wsum[wid] + incl - cnt;
  #pragma unroll
  for (int e = 0; e < 2; ++e) {
    if (f[e]) {
      int s = t * 2 + e;
      u64 key = best[s];
      best_idx[b * Q_ + excl] = (int)(~(u32)key);
      best_sc[b * Q_ + excl] = __uint_as_float((u32)(key >> 32));
      excl++;
    }
  }
  __syncthreads();
  int n = s_tot;

  for (int p = wid; p < Q_; p += 16) {
    float* orow = out_sig + ((size_t)b * Q_ + p) * C_;
    if (p < n) {
      int row = best_idx[b * Q_ + p];
      float4 v = *reinterpret_cast<const float4*>(sig + ((size_t)b * Q_ + row) * C_ + lane * 4);
      *reinterpret_cast<float4*>(orow + lane * 4) = v;
      if (lane == 0) {
        out_mask[b * Q_ + p] = 1.0f;
        out_scores[b * Q_ + p] = best_sc[b * Q_ + p];
      }
    } else {
      *reinterpret_cast<float4*>(orow + lane * 4) = make_float4(0.f, 0.f, 0.f, 0.f);
      if (lane == 0) {
        out_mask[b * Q_ + p] = 0.0f;
        out_scores[b * Q_ + p] = 0.0f;
      }
    }
  }
}

// ---------------- Fallback kernels (small-ws paths; r15 verbatim) ----------
__global__ __launch_bounds__(256)
void k_prep(const float* __restrict__ sig, const int* __restrict__ sel_idx,
            const int* __restrict__ sel_cnt, unsigned short* __restrict__ nsig,
            u32* __restrict__ rowmin) {
  int b = blockIdx.y;
  int p = blockIdx.x * 4 + (threadIdx.x >> 6);
  int lane = threadIdx.x & 63;
  int S = sel_cnt[b];
  int Spad = (S + 63) & ~63;
  int Spad128 = (S + 127) & ~127;
  if (p < Spad && lane == 0) rowmin[b * QPAD + p] = 0xFFFFFFFFu;
  if (p >= Spad128 || p >= QPAD) return;
  unsigned short* dst = nsig + ((size_t)b * QPAD + p) * C_;
  if (p >= S) {
    *reinterpret_cast<uint2*>(dst + lane * 4) = make_uint2(0u, 0u);
    return;
  }
  int row = sel_idx[b * Q_ + p];
  const float* src = sig + ((size_t)b * Q_ + row) * C_;
  float4 v = *reinterpret_cast<const float4*>(src + lane * 4);
  float ss = v.x * v.x + v.y * v.y + v.z * v.z + v.w * v.w;
  #pragma unroll
  for (int m = 32; m; m >>= 1) ss += __shfl_xor(ss, m, 64);
  float inv = 1.0f / fmaxf(sqrtf(ss), 1e-12f);
  __hip_bfloat16 h0 = __float2bfloat16(v.x * inv);
  __hip_bfloat16 h1 = __float2bfloat16(v.y * inv);
  __hip_bfloat16 h2 = __float2bfloat16(v.z * inv);
  __hip_bfloat16 h3 = __float2bfloat16(v.w * inv);
  unsigned short u0, u1, u2, u3;
  __builtin_memcpy(&u0, &h0, 2); __builtin_memcpy(&u1, &h1, 2);
  __builtin_memcpy(&u2, &h2, 2); __builtin_memcpy(&u3, &h3, 2);
  uint2 wv;
  wv.x = (u32)u0 | ((u32)u1 << 16);
  wv.y = (u32)u2 | ((u32)u3 << 16);
  *reinterpret_cast<uint2*>(dst + lane * 4) = wv;
}

__global__ __launch_bounds__(256)
void k_ccgather(const float* __restrict__ sig, const float* __restrict__ logits,
                const int* __restrict__ sel_idx, const int* __restrict__ sel_cnt,
                const u64* __restrict__ adj, const u32* __restrict__ rowmin,
                float* __restrict__ out_sig, float* __restrict__ out_mask,
                float* __restrict__ out_scores) {
  const int b = blockIdx.y, g = blockIdx.x;
  const int t = threadIdx.x, lane = t & 63, wid = t >> 6;
  __shared__ int lab[Q_];
  __shared__ int lab2[Q_];
  __shared__ u64 best[Q_];
  __shared__ int wsum[4];
  __shared__ int s_tot;
  __shared__ int s_dirty;

  const int S = sel_cnt[b];
  if (t == 0) s_dirty = 0;
  __syncthreads();
  for (int s = t; s < S; s += 256)
    if (rowmin[b * QPAD + s] != (u32)s) s_dirty = 1;
  __syncthreads();

  const int p = g * 4 + wid;
  float* orow = out_sig + ((size_t)b * Q_ + p) * C_;

  if (!s_dirty) {
    if (p < S) {
      int row = sel_idx[b * Q_ + p];
      float4 v = *reinterpret_cast<const float4*>(sig + ((size_t)b * Q_ + row) * C_ + lane * 4);
      *reinterpret_cast<float4*>(orow + lane * 4) = v;
      if (lane == 0) {
        out_mask[b * Q_ + p] = 1.0f;
        out_scores[b * Q_ + p] = 1.0f / (1.0f + expf(-logits[b * Q_ + row]));
      }
    } else {
      *reinterpret_cast<float4*>(orow + lane * 4) = make_float4(0.f, 0.f, 0.f, 0.f);
      if (lane == 0) {
        out_mask[b * Q_ + p] = 0.0f;
        out_scores[b * Q_ + p] = 0.0f;
      }
    }
    return;
  }

  const int nw = (S + 63) >> 6;
  const u64* arow0 = adj + (size_t)b * Q_ * WPR;
  __shared__ int s_chg;

  if (t == 0) s_chg = 1;
  for (int s = t; s < S; s += 256) {
    u32 m = rowmin[b * QPAD + s];
    lab[s] = (int)(((u32)s < m) ? (u32)s : m);
  }
  __syncthreads();
  for (int iter = 0; iter < Q_ + 2; ++iter) {
    if (t == 0) s_chg = 0;
    __syncthreads();
    for (int s = t; s < S; s += 256) {
      int m = lab[s];
      const u64* row = arow0 + (size_t)s * WPR;
      for (int w = 0; w < nw; ++w) {
        u64 msk = row[w];
        while (msk) {
          int j = (w << 6) + __builtin_ctzll(msk);
          int lj = lab[j];
          m = (lj < m) ? lj : m;
          msk &= msk - 1;
        }
      }
      lab2[s] = m;
      if (m != lab[s]) s_chg = 1;
    }
    __syncthreads();
    int ch = s_chg;
    for (int s = t; s < S; s += 256) lab[s] = lab2[s];
    __syncthreads();
    if (!ch) break;
  }

  for (int s = t; s < S; s += 256) best[s] = 0ull;
  __syncthreads();
  const int* sidx = sel_idx + b * Q_;
  for (int s = t; s < S; s += 256) {
    int orig = sidx[s];
    float sc = 1.0f / (1.0f + expf(-logits[b * Q_ + orig]));
    u64 key = ((u64)__float_as_uint(sc) << 32) | (u32)(~(u32)orig);
    atomicMax(&best[lab[s]], key);
  }
  __syncthreads();

  __shared__ int slot[4];
  int rf[8]; int rcnt = 0;
  #pragma unroll
  for (int e = 0; e < 8; ++e) {
    int s = t * 8 + e;
    int fl = (s < S && lab[s] == s) ? 1 : 0;
    rf[e] = fl; rcnt += fl;
  }
  int rincl = rcnt;
  #pragma unroll
  for (int d = 1; d < 64; d <<= 1) {
    int v = __shfl_up(rincl, d, 64);
    if (lane >= d) rincl += v;
  }
  if (t < 4) slot[t] = -1;
  if (lane == 63) wsum[wid] = rincl;
  __syncthreads();
  if (t == 0) {
    int acc = 0;
    #pragma unroll
    for (int i = 0; i < 4; ++i) { int v = wsum[i]; wsum[i] = acc; acc += v; }
    s_tot = acc;
  }
  __syncthreads();
  int rex = wsum[wid] + rincl - rcnt;
  #pragma unroll
  for (int e = 0; e < 8; ++e) {
    if (rf[e]) {
      if (rex >= g * 4 && rex < g * 4 + 4) slot[rex - g * 4] = t * 8 + e;
      rex++;
    }
  }
  __syncthreads();
  int n = s_tot;

  if (p < n) {
    u64 key = best[slot[wid]];
    int orig = (int)(~(u32)key);
    float4 v = *reinterpret_cast<const float4*>(sig + ((size_t)b * Q_ + orig) * C_ + lane * 4);
    *reinterpret_cast<float4*>(orow + lane * 4) = v;
    if (lane == 0) {
      out_mask[b * Q_ + p] = 1.0f;
      out_scores[b * Q_ + p] = __uint_as_float((u32)(key >> 32));
    }
  } else {
    *reinterpret_cast<float4*>(orow + lane * 4) = make_float4(0.f, 0.f, 0.f, 0.f);
    if (lane == 0) {
      out_mask[b * Q_ + p] = 0.0f;
      out_scores[b * Q_ + p] = 0.0f;
    }
  }
}

extern "C" void kernel_launch(void* const* d_in, const int* in_sizes, int n_in,
                              void* d_out, int out_size, void* d_ws, size_t ws_size,
                              hipStream_t stream) {
  const float* p0 = (const float*)d_in[0];
  const float* p1 = (const float*)d_in[1];
  const float* sig;  const float* logits;
  if (in_sizes[0] == B_ * Q_ * C_) { sig = p0; logits = p1; }
  else                             { sig = p1; logits = p0; }

  float* out = (float*)d_out;
  float* out_mask   = out + OUT_SIG_ELEMS;
  float* out_scores = out + OUT_SIG_ELEMS + B_ * Q_;

  char* w = (char*)d_ws;
  int* sel_cnt = (int*)w;  w += 256;
  int* dirty   = (int*)w;  w += 256;
  int* sel_idx = (int*)w;  w += B_ * Q_ * 4;

  dim3 gp(QPAD / 4, B_);
  dim3 gg(Q_ / 4, B_);

  // Path A needs all scratch in ws (outputs written early):
  const size_t need_A = 512 + 3 * (size_t)B_ * Q_ * 4 + (size_t)B_ * QPAD * 4 +
                        (size_t)B_ * Q_ * WPR * 8 + (size_t)B_ * QPAD * C_ * 2;
  // Path B: adj/rowmin in ws, nsig in d_out scratch, outputs last:
  const size_t need_B = 512 + (size_t)B_ * Q_ * 4 + (size_t)B_ * QPAD * 4 +
                        (size_t)B_ * Q_ * WPR * 8;

  if (ws_size >= need_A) {
    int* best_idx  = (int*)w;   w += B_ * Q_ * 4;
    float* best_sc = (float*)w; w += B_ * Q_ * 4;
    u32* rowmin = (u32*)w;      w += (size_t)B_ * QPAD * 4;
    u64* adj    = (u64*)w;      w += (size_t)B_ * Q_ * WPR * 8;
    unsigned short* nsig = (unsigned short*)w;

    k_compact<<<B_, 256, 0, stream>>>(logits, sel_idx, sel_cnt, dirty);
    k_prepg<<<gp, 256, 0, stream>>>(sig, logits, sel_idx, sel_cnt, nsig, rowmin,
                                    out, out_mask, out_scores);
    k_sim<<<B_ * NTRI, 256, 0, stream>>>(nsig, sel_cnt, adj, rowmin, dirty);
    k_fix<<<B_, 1024, 0, stream>>>(sig, logits, sel_idx, sel_cnt, adj, rowmin,
                                   dirty, best_idx, best_sc,
                                   out, out_mask, out_scores);
  } else if (ws_size >= need_B) {
    u32* rowmin = (u32*)w;  w += (size_t)B_ * QPAD * 4;
    u64* adj    = (u64*)w;
    unsigned short* nsig = (unsigned short*)((char*)d_out + (size_t)(8u << 20));

    k_compact<<<B_, 256, 0, stream>>>(logits, sel_idx, sel_cnt, dirty);
    k_prep<<<gp, 256, 0, stream>>>(sig, sel_idx, sel_cnt, nsig, rowmin);
    k_sim<<<B_ * NTRI, 256, 0, stream>>>(nsig, sel_cnt, adj, rowmin, dirty);
    k_ccgather<<<gg, 256, 0, stream>>>(sig, logits, sel_idx, sel_cnt, adj, rowmin,
                                       out, out_mask, out_scores);
  } else {
    // minimal-ws: adj in d_out (dirty-path reads only), rowmin in ws (fits).
    u64* adj    = (u64*)d_out;
    u32* rowmin = (u32*)w;
    unsigned short* nsig = (unsigned short*)((char*)d_out + (size_t)(8u << 20));

    k_compact<<<B_, 256, 0, stream>>>(logits, sel_idx, sel_cnt, dirty);
    k_prep<<<gp, 256, 0, stream>>>(sig, sel_idx, sel_cnt, nsig, rowmin);
    k_sim<<<B_ * NTRI, 256, 0, stream>>>(nsig, sel_cnt, adj, rowmin, dirty);
    k_ccgather<<<gg, 256, 0, stream>>>(sig, logits, sel_idx, sel_cnt, adj, rowmin,
                                       out, out_mask, out_scores);
  }
}

// Round 19
// 40.639 us; speedup vs baseline: 1.1313x; 1.0841x over previous
//
#include <hip/hip_runtime.h>
#include <hip/hip_bf16.h>
#include <stdint.h>

#define B_ 16
#define Q_ 1800
#define C_ 256
#define WPR 29            // u64 words per adjacency row = ceil(1800/64)
#define QPAD 1856         // padded compacted-row capacity
#define TBK 15            // 128-wide tiles per dim
#define NTRI 120          // triangular tile count = TBK*(TBK+1)/2
#define OUT_SIG_ELEMS (B_*Q_*C_)

typedef unsigned long long u64;
typedef unsigned int u32;
typedef __attribute__((ext_vector_type(8))) short bf16x8;   // 8 bf16 (4 VGPRs)
typedef __attribute__((ext_vector_type(4))) float f32x4;    // 4 fp32 acc

// ---------------- K1: selection + compaction (16 blocks; sign-test) --------
__global__ __launch_bounds__(256)
void k_compact(const float* __restrict__ logits,
               int* __restrict__ sel_idx, int* __restrict__ sel_cnt,
               int* __restrict__ dirty) {
  int b = blockIdx.x, t = threadIdx.x;
  int lane = t & 63, wid = t >> 6;
  __shared__ int wsum[4];
  __shared__ int s_tot;
  __shared__ u64 kw[4];
  const float* lgb = logits + b * Q_;
  if (t == 0) dirty[b] = 0;

  int f[8]; int cnt = 0;
  #pragma unroll
  for (int e = 0; e < 8; ++e) {
    int q = t * 8 + e; int fl = 0;
    if (q < Q_) fl = (lgb[q] >= 0.0f) ? 1 : 0;   // == (sigmoid >= 0.5)
    f[e] = fl; cnt += fl;
  }
  int incl = cnt;
  #pragma unroll
  for (int d = 1; d < 64; d <<= 1) {
    int v = __shfl_up(incl, d, 64);
    if (lane >= d) incl += v;
  }
  if (lane == 63) wsum[wid] = incl;
  __syncthreads();
  if (t == 0) {
    int acc = 0;
    #pragma unroll
    for (int i = 0; i < 4; ++i) { int v = wsum[i]; wsum[i] = acc; acc += v; }
    s_tot = acc;
  }
  __syncthreads();
  int excl = wsum[wid] + incl - cnt;
  int total = s_tot;

  if (total > 0) {
    #pragma unroll
    for (int e = 0; e < 8; ++e) {
      if (f[e]) { sel_idx[b * Q_ + excl] = t * 8 + e; excl++; }
    }
    if (t == 0) sel_cnt[b] = total;
  } else {                        // rare fallback: true score-ordered argmax
    u64 mk = 0;
    for (int q = t; q < Q_; q += 256) {
      float sc = 1.0f / (1.0f + expf(-lgb[q]));
      u64 key = ((u64)__float_as_uint(sc) << 32) | (u32)(~(u32)q); // max sc, min idx
      mk = (mk > key) ? mk : key;
    }
    #pragma unroll
    for (int d = 1; d < 64; d <<= 1) { u64 o = __shfl_xor(mk, d, 64); mk = (o > mk) ? o : mk; }
    if (lane == 0) kw[wid] = mk;
    __syncthreads();
    if (t == 0) {
      u64 m2 = kw[0];
      #pragma unroll
      for (int i = 1; i < 4; ++i) m2 = (kw[i] > m2) ? kw[i] : m2;
      sel_idx[b * Q_] = (int)(~(u32)m2);
      sel_cnt[b] = 1;
    }
  }
}

// ---------------- K2 (big-ws): prep + SPECULATIVE gather -------------------
__global__ __launch_bounds__(256)
void k_prepg(const float* __restrict__ sig, const float* __restrict__ logits,
             const int* __restrict__ sel_idx, const int* __restrict__ sel_cnt,
             unsigned short* __restrict__ nsig, u32* __restrict__ rowmin,
             float* __restrict__ out_sig, float* __restrict__ out_mask,
             float* __restrict__ out_scores) {
  int b = blockIdx.y;
  int p = blockIdx.x * 4 + (threadIdx.x >> 6);
  int lane = threadIdx.x & 63;
  int S = sel_cnt[b];
  int Spad = (S + 63) & ~63;
  int Spad128 = (S + 127) & ~127;

  if (p < Spad && lane == 0) rowmin[b * QPAD + p] = 0xFFFFFFFFu;

  if (p < S) {
    int row = sel_idx[b * Q_ + p];
    const float* src = sig + ((size_t)b * Q_ + row) * C_;
    float4 v = *reinterpret_cast<const float4*>(src + lane * 4);

    float* orow = out_sig + ((size_t)b * Q_ + p) * C_;      // speculative out
    *reinterpret_cast<float4*>(orow + lane * 4) = v;
    if (lane == 0) {
      out_mask[b * Q_ + p] = 1.0f;
      out_scores[b * Q_ + p] = 1.0f / (1.0f + expf(-logits[b * Q_ + row]));
    }

    float ss = v.x * v.x + v.y * v.y + v.z * v.z + v.w * v.w;
    #pragma unroll
    for (int m = 32; m; m >>= 1) ss += __shfl_xor(ss, m, 64);
    float inv = 1.0f / fmaxf(sqrtf(ss), 1e-12f);
    __hip_bfloat16 h0 = __float2bfloat16(v.x * inv);
    __hip_bfloat16 h1 = __float2bfloat16(v.y * inv);
    __hip_bfloat16 h2 = __float2bfloat16(v.z * inv);
    __hip_bfloat16 h3 = __float2bfloat16(v.w * inv);
    unsigned short u0, u1, u2, u3;
    __builtin_memcpy(&u0, &h0, 2); __builtin_memcpy(&u1, &h1, 2);
    __builtin_memcpy(&u2, &h2, 2); __builtin_memcpy(&u3, &h3, 2);
    uint2 wv;
    wv.x = (u32)u0 | ((u32)u1 << 16);
    wv.y = (u32)u2 | ((u32)u3 << 16);
    *reinterpret_cast<uint2*>(nsig + ((size_t)b * QPAD + p) * C_ + lane * 4) = wv;
  } else {
    if (p < Spad128 && p < QPAD)                             // zero to tile edge
      *reinterpret_cast<uint2*>(nsig + ((size_t)b * QPAD + p) * C_ + lane * 4) =
          make_uint2(0u, 0u);
    if (p < Q_) {                                            // zero out row
      float* orow = out_sig + ((size_t)b * Q_ + p) * C_;
      *reinterpret_cast<float4*>(orow + lane * 4) = make_float4(0.f, 0.f, 0.f, 0.f);
      if (lane == 0) {
        out_mask[b * Q_ + p] = 0.0f;
        out_scores[b * Q_ + p] = 0.0f;
      }
    }
  }
}

// ---------------- K3: LDS-staged MFMA cosine-sim, triangular ---------------
// Interior tiles (105/120) use the r16 unguarded staging loop; only edge
// tiles (tib==14 || tjb==14, rows up to 1919 >= QPAD) pay the row-guard.
__global__ __launch_bounds__(256)
void k_sim(const unsigned short* __restrict__ nsig, const int* __restrict__ sel_cnt,
           u64* __restrict__ adj, u32* __restrict__ rowmin,
           int* __restrict__ dirty) {
  int lin = blockIdx.x;
  int b = lin & 15;
  int u = lin >> 4, tib = 0;
  while (u >= TBK - tib) { u -= TBK - tib; ++tib; }
  int tjb = tib + u;                          // tib <= tjb < TBK
  int S = sel_cnt[b];
  if (tjb * 128 >= S) return;                 // implies tib*128 < S
  const bool diag = (tib == tjb);
  const bool guard = (tjb == TBK - 1);        // tib<=tjb, so covers tib==14 too

  __shared__ uint4 Alds[2048];
  __shared__ uint4 Blds[2048];
  __shared__ u64 adjtile[4][64];

  const int t = threadIdx.x;
  const int wv = t >> 6, lane = t & 63;
  const int lr = lane & 15, lg = lane >> 4;

  const int i1 = tib * 128 + (wv >> 1) * 64;
  const int j1 = tjb * 128 + (wv & 1) * 64;
  const bool live = (i1 < S) && (j1 < S);

  const char* gbase = (const char*)(nsig + (size_t)b * QPAD * C_);
  const char* arow = gbase + (size_t)tib * 128 * 512;
  const char* brow = gbase + (size_t)tjb * 128 * 512;

  f32x4 acc[4][4];
  #pragma unroll
  for (int rs = 0; rs < 4; ++rs)
    #pragma unroll
    for (int cg = 0; cg < 4; ++cg) acc[rs][cg] = (f32x4){0.f, 0.f, 0.f, 0.f};

  const int ra0 = (wv >> 1) * 64;
  const int rb0 = (wv & 1) * 64;
  const char* Bbase = reinterpret_cast<const char*>(diag ? Alds : Blds);

  for (int kh = 0; kh < 2; ++kh) {
    if (!guard) {                             // fast path (r16 verbatim)
      #pragma unroll
      for (int it = 0; it < 8; ++it) {
        int o = it * 4096 + t * 16;
        int r = o >> 8;
        int w = o & 255;
        int sw = o ^ ((r & 7) << 4);          // swizzled LDS byte offset
        uint4 va = *reinterpret_cast<const uint4*>(arow + (size_t)r * 512 + kh * 256 + w);
        Alds[sw >> 4] = va;
        if (!diag) {
          uint4 vb = *reinterpret_cast<const uint4*>(brow + (size_t)r * 512 + kh * 256 + w);
          Blds[sw >> 4] = vb;
        }
      }
    } else {                                  // edge tiles: row-guarded
      #pragma unroll
      for (int it = 0; it < 8; ++it) {
        int o = it * 4096 + t * 16;
        int r = o >> 8;
        int w = o & 255;
        int sw = o ^ ((r & 7) << 4);
        uint4 zz = make_uint4(0u, 0u, 0u, 0u);
        uint4 va = (tib * 128 + r < QPAD)
            ? *reinterpret_cast<const uint4*>(arow + (size_t)r * 512 + kh * 256 + w) : zz;
        Alds[sw >> 4] = va;
        if (!diag) {
          uint4 vb = (tjb * 128 + r < QPAD)
              ? *reinterpret_cast<const uint4*>(brow + (size_t)r * 512 + kh * 256 + w) : zz;
          Blds[sw >> 4] = vb;
        }
      }
    }
    __syncthreads();
    if (live) {
      #pragma unroll
      for (int ks = 0; ks < 4; ++ks) {
        bf16x8 af[4], bf[4];
        #pragma unroll
        for (int rs = 0; rs < 4; ++rs) {
          int r = ra0 + rs * 16 + lr;
          int byte = r * 256 + ((ks * 64 + lg * 16) ^ ((r & 7) << 4));
          af[rs] = *reinterpret_cast<const bf16x8*>(
              reinterpret_cast<const char*>(Alds) + byte);
        }
        #pragma unroll
        for (int cg = 0; cg < 4; ++cg) {
          int r = rb0 + cg * 16 + lr;
          int byte = r * 256 + ((ks * 64 + lg * 16) ^ ((r & 7) << 4));
          bf[cg] = *reinterpret_cast<const bf16x8*>(Bbase + byte);
        }
        #pragma unroll
        for (int rs = 0; rs < 4; ++rs)
          #pragma unroll
          for (int cg = 0; cg < 4; ++cg)
            acc[rs][cg] = __builtin_amdgcn_mfma_f32_16x16x32_bf16(
                af[rs], bf[cg], acc[rs][cg], 0, 0, 0);
      }
    }
    __syncthreads();
  }

  if (!live) return;
  adjtile[wv][lane] = 0ull;                   // wave-private strip
  #pragma unroll
  for (int rs = 0; rs < 4; ++rs) {
    #pragma unroll
    for (int j = 0; j < 4; ++j) {
      u64 bits = 0ull;
      if (acc[rs][0][j] >= 0.8f) bits |= 1ull << (0  + lr);
      if (acc[rs][1][j] >= 0.8f) bits |= 1ull << (16 + lr);
      if (acc[rs][2][j] >= 0.8f) bits |= 1ull << (32 + lr);
      if (acc[rs][3][j] >= 0.8f) bits |= 1ull << (48 + lr);
      if (bits) atomicOr(&adjtile[wv][rs * 16 + lg * 4 + j], bits);
    }
  }
  int gi = i1 + lane;
  u64 word = adjtile[wv][lane];
  u64 selfbit = (i1 == j1) ? (1ull << lane) : 0ull;
  bool offd = (gi < S) && ((word & ~selfbit) != 0ull);
  if (__any(offd) && lane == 0) atomicOr(&dirty[b], 1);
  if (gi < S) {
    adj[((size_t)b * Q_ + gi) * WPR + (j1 >> 6)] = word;
    if (word) atomicMin(&rowmin[b * QPAD + gi], (u32)(j1 + __builtin_ctzll(word)));
  }
  if (!diag) {                                // mirrored word via bit-transpose
    u64 tw = 0ull;
    for (int i = 0; i < 64; ++i)
      tw |= ((adjtile[wv][i] >> lane) & 1ull) << i;
    int gj = j1 + lane;
    if (gj < S) {
      adj[((size_t)b * Q_ + gj) * WPR + (i1 >> 6)] = tw;
      if (tw) atomicMin(&rowmin[b * QPAD + gj], (u32)(i1 + __builtin_ctzll(tw)));
    }
  }
}

// ---------------- K4: fix — exits instantly when clean ---------------------
__global__ __launch_bounds__(1024)
void k_fix(const float* __restrict__ sig, const float* __restrict__ logits,
           const int* __restrict__ sel_idx, const int* __restrict__ sel_cnt,
           const u64* __restrict__ adj, const u32* __restrict__ rowmin,
           const int* __restrict__ dirty,
           int* __restrict__ best_idx, float* __restrict__ best_sc,
           float* __restrict__ out_sig, float* __restrict__ out_mask,
           float* __restrict__ out_scores) {
  int b = blockIdx.x;
  if (!dirty[b]) return;                      // clean: ~free
  int t = threadIdx.x;
  int lane = t & 63, wid = t >> 6;
  __shared__ int lab[Q_];
  __shared__ int lab2[Q_];
  __shared__ u64 best[Q_];
  __shared__ int wsum[16];
  __shared__ int s_tot;
  __shared__ int s_changed;

  int S = sel_cnt[b];
  int nw = (S + 63) >> 6;
  const u64* arow0 = adj + (size_t)b * Q_ * WPR;

  for (int s = t; s < S; s += 1024) {
    u32 m = rowmin[b * QPAD + s];
    lab[s] = (int)(((u32)s < m) ? (u32)s : m);
  }
  __syncthreads();
  for (int iter = 0; iter < Q_ + 2; ++iter) {
    if (t == 0) s_changed = 0;
    __syncthreads();
    for (int s = t; s < S; s += 1024) {
      int m = lab[s];
      const u64* row = arow0 + (size_t)s * WPR;
      for (int w = 0; w < nw; ++w) {
        u64 msk = row[w];
        while (msk) {
          int j = (w << 6) + __builtin_ctzll(msk);
          int lj = lab[j];
          m = (lj < m) ? lj : m;
          msk &= msk - 1;
        }
      }
      lab2[s] = m;
      if (m != lab[s]) s_changed = 1;
    }
    __syncthreads();
    int ch = s_changed;
    for (int s = t; s < S; s += 1024) lab[s] = lab2[s];
    __syncthreads();
    if (!ch) break;
  }

  for (int s = t; s < S; s += 1024) best[s] = 0ull;
  __syncthreads();
  const int* sidx = sel_idx + b * Q_;
  for (int s = t; s < S; s += 1024) {
    int orig = sidx[s];
    float sc = 1.0f / (1.0f + expf(-logits[b * Q_ + orig]));
    u64 key = ((u64)__float_as_uint(sc) << 32) | (u32)(~(u32)orig);
    atomicMax(&best[lab[s]], key);
  }
  __syncthreads();

  int f[2]; int cnt = 0;
  #pragma unroll
  for (int e = 0; e < 2; ++e) {
    int s = t * 2 + e;
    int fl = (s < S && lab[s] == s) ? 1 : 0;
    f[e] = fl; cnt += fl;
  }
  int incl = cnt;
  #pragma unroll
  for (int d = 1; d < 64; d <<= 1) {
    int v = __shfl_up(incl, d, 64);
    if (lane >= d) incl += v;
  }
  if (lane == 63) wsum[wid] = incl;
  __syncthreads();
  if (t == 0) {
    int acc = 0;
    #pragma unroll
    for (int i = 0; i < 16; ++i) { int v = wsum[i]; wsum[i] = acc; acc += v; }
    s_tot = acc;
  }
  __syncthreads();
  int excl = wsum[wid] + incl - cnt;
  #pragma unroll
  for (int e = 0; e < 2; ++e) {
    if (f[e]) {
      int s = t * 2 + e;
      u64 key = best[s];
      best_idx[b * Q_ + excl] = (int)(~(u32)key);
      best_sc[b * Q_ + excl] = __uint_as_float((u32)(key >> 32));
      excl++;
    }
  }
  __syncthreads();
  int n = s_tot;

  for (int p = wid; p < Q_; p += 16) {
    float* orow = out_sig + ((size_t)b * Q_ + p) * C_;
    if (p < n) {
      int row = best_idx[b * Q_ + p];
      float4 v = *reinterpret_cast<const float4*>(sig + ((size_t)b * Q_ + row) * C_ + lane * 4);
      *reinterpret_cast<float4*>(orow + lane * 4) = v;
      if (lane == 0) {
        out_mask[b * Q_ + p] = 1.0f;
        out_scores[b * Q_ + p] = best_sc[b * Q_ + p];
      }
    } else {
      *reinterpret_cast<float4*>(orow + lane * 4) = make_float4(0.f, 0.f, 0.f, 0.f);
      if (lane == 0) {
        out_mask[b * Q_ + p] = 0.0f;
        out_scores[b * Q_ + p] = 0.0f;
      }
    }
  }
}

// ---------------- Fallback kernels (small-ws paths) ------------------------
__global__ __launch_bounds__(256)
void k_prep(const float* __restrict__ sig, const int* __restrict__ sel_idx,
            const int* __restrict__ sel_cnt, unsigned short* __restrict__ nsig,
            u32* __restrict__ rowmin) {
  int b = blockIdx.y;
  int p = blockIdx.x * 4 + (threadIdx.x >> 6);
  int lane = threadIdx.x & 63;
  int S = sel_cnt[b];
  int Spad = (S + 63) & ~63;
  int Spad128 = (S + 127) & ~127;
  if (p < Spad && lane == 0) rowmin[b * QPAD + p] = 0xFFFFFFFFu;
  if (p >= Spad128 || p >= QPAD) return;
  unsigned short* dst = nsig + ((size_t)b * QPAD + p) * C_;
  if (p >= S) {
    *reinterpret_cast<uint2*>(dst + lane * 4) = make_uint2(0u, 0u);
    return;
  }
  int row = sel_idx[b * Q_ + p];
  const float* src = sig + ((size_t)b * Q_ + row) * C_;
  float4 v = *reinterpret_cast<const float4*>(src + lane * 4);
  float ss = v.x * v.x + v.y * v.y + v.z * v.z + v.w * v.w;
  #pragma unroll
  for (int m = 32; m; m >>= 1) ss += __shfl_xor(ss, m, 64);
  float inv = 1.0f / fmaxf(sqrtf(ss), 1e-12f);
  __hip_bfloat16 h0 = __float2bfloat16(v.x * inv);
  __hip_bfloat16 h1 = __float2bfloat16(v.y * inv);
  __hip_bfloat16 h2 = __float2bfloat16(v.z * inv);
  __hip_bfloat16 h3 = __float2bfloat16(v.w * inv);
  unsigned short u0, u1, u2, u3;
  __builtin_memcpy(&u0, &h0, 2); __builtin_memcpy(&u1, &h1, 2);
  __builtin_memcpy(&u2, &h2, 2); __builtin_memcpy(&u3, &h3, 2);
  uint2 wv;
  wv.x = (u32)u0 | ((u32)u1 << 16);
  wv.y = (u32)u2 | ((u32)u3 << 16);
  *reinterpret_cast<uint2*>(dst + lane * 4) = wv;
}

__global__ __launch_bounds__(256)
void k_ccgather(const float* __restrict__ sig, const float* __restrict__ logits,
                const int* __restrict__ sel_idx, const int* __restrict__ sel_cnt,
                const u64* __restrict__ adj, const u32* __restrict__ rowmin,
                float* __restrict__ out_sig, float* __restrict__ out_mask,
                float* __restrict__ out_scores) {
  const int b = blockIdx.y, g = blockIdx.x;
  const int t = threadIdx.x, lane = t & 63, wid = t >> 6;
  __shared__ int lab[Q_];
  __shared__ int lab2[Q_];
  __shared__ u64 best[Q_];
  __shared__ int wsum[4];
  __shared__ int s_tot;
  __shared__ int s_dirty;

  const int S = sel_cnt[b];
  if (t == 0) s_dirty = 0;
  __syncthreads();
  for (int s = t; s < S; s += 256)
    if (rowmin[b * QPAD + s] != (u32)s) s_dirty = 1;
  __syncthreads();

  const int p = g * 4 + wid;
  float* orow = out_sig + ((size_t)b * Q_ + p) * C_;

  if (!s_dirty) {
    if (p < S) {
      int row = sel_idx[b * Q_ + p];
      float4 v = *reinterpret_cast<const float4*>(sig + ((size_t)b * Q_ + row) * C_ + lane * 4);
      *reinterpret_cast<float4*>(orow + lane * 4) = v;
      if (lane == 0) {
        out_mask[b * Q_ + p] = 1.0f;
        out_scores[b * Q_ + p] = 1.0f / (1.0f + expf(-logits[b * Q_ + row]));
      }
    } else {
      *reinterpret_cast<float4*>(orow + lane * 4) = make_float4(0.f, 0.f, 0.f, 0.f);
      if (lane == 0) {
        out_mask[b * Q_ + p] = 0.0f;
        out_scores[b * Q_ + p] = 0.0f;
      }
    }
    return;
  }

  const int nw = (S + 63) >> 6;
  const u64* arow0 = adj + (size_t)b * Q_ * WPR;
  __shared__ int s_chg;

  if (t == 0) s_chg = 1;
  for (int s = t; s < S; s += 256) {
    u32 m = rowmin[b * QPAD + s];
    lab[s] = (int)(((u32)s < m) ? (u32)s : m);
  }
  __syncthreads();
  for (int iter = 0; iter < Q_ + 2; ++iter) {
    if (t == 0) s_chg = 0;
    __syncthreads();
    for (int s = t; s < S; s += 256) {
      int m = lab[s];
      const u64* row = arow0 + (size_t)s * WPR;
      for (int w = 0; w < nw; ++w) {
        u64 msk = row[w];
        while (msk) {
          int j = (w << 6) + __builtin_ctzll(msk);
          int lj = lab[j];
          m = (lj < m) ? lj : m;
          msk &= msk - 1;
        }
      }
      lab2[s] = m;
      if (m != lab[s]) s_chg = 1;
    }
    __syncthreads();
    int ch = s_chg;
    for (int s = t; s < S; s += 256) lab[s] = lab2[s];
    __syncthreads();
    if (!ch) break;
  }

  for (int s = t; s < S; s += 256) best[s] = 0ull;
  __syncthreads();
  const int* sidx = sel_idx + b * Q_;
  for (int s = t; s < S; s += 256) {
    int orig = sidx[s];
    float sc = 1.0f / (1.0f + expf(-logits[b * Q_ + orig]));
    u64 key = ((u64)__float_as_uint(sc) << 32) | (u32)(~(u32)orig);
    atomicMax(&best[lab[s]], key);
  }
  __syncthreads();

  __shared__ int slot[4];
  int rf[8]; int rcnt = 0;
  #pragma unroll
  for (int e = 0; e < 8; ++e) {
    int s = t * 8 + e;
    int fl = (s < S && lab[s] == s) ? 1 : 0;
    rf[e] = fl; rcnt += fl;
  }
  int rincl = rcnt;
  #pragma unroll
  for (int d = 1; d < 64; d <<= 1) {
    int v = __shfl_up(rincl, d, 64);
    if (lane >= d) rincl += v;
  }
  if (t < 4) slot[t] = -1;
  if (lane == 63) wsum[wid] = rincl;
  __syncthreads();
  if (t == 0) {
    int acc = 0;
    #pragma unroll
    for (int i = 0; i < 4; ++i) { int v = wsum[i]; wsum[i] = acc; acc += v; }
    s_tot = acc;
  }
  __syncthreads();
  int rex = wsum[wid] + rincl - rcnt;
  #pragma unroll
  for (int e = 0; e < 8; ++e) {
    if (rf[e]) {
      if (rex >= g * 4 && rex < g * 4 + 4) slot[rex - g * 4] = t * 8 + e;
      rex++;
    }
  }
  __syncthreads();
  int n = s_tot;

  if (p < n) {
    u64 key = best[slot[wid]];
    int orig = (int)(~(u32)key);
    float4 v = *reinterpret_cast<const float4*>(sig + ((size_t)b * Q_ + orig) * C_ + lane * 4);
    *reinterpret_cast<float4*>(orow + lane * 4) = v;
    if (lane == 0) {
      out_mask[b * Q_ + p] = 1.0f;
      out_scores[b * Q_ + p] = __uint_as_float((u32)(key >> 32));
    }
  } else {
    *reinterpret_cast<float4*>(orow + lane * 4) = make_float4(0.f, 0.f, 0.f, 0.f);
    if (lane == 0) {
      out_mask[b * Q_ + p] = 0.0f;
      out_scores[b * Q_ + p] = 0.0f;
    }
  }
}

extern "C" void kernel_launch(void* const* d_in, const int* in_sizes, int n_in,
                              void* d_out, int out_size, void* d_ws, size_t ws_size,
                              hipStream_t stream) {
  const float* p0 = (const float*)d_in[0];
  const float* p1 = (const float*)d_in[1];
  const float* sig;  const float* logits;
  if (in_sizes[0] == B_ * Q_ * C_) { sig = p0; logits = p1; }
  else                             { sig = p1; logits = p0; }

  float* out = (float*)d_out;
  float* out_mask   = out + OUT_SIG_ELEMS;
  float* out_scores = out + OUT_SIG_ELEMS + B_ * Q_;

  char* w = (char*)d_ws;
  int* sel_cnt = (int*)w;  w += 256;
  int* dirty   = (int*)w;  w += 256;
  int* sel_idx = (int*)w;  w += B_ * Q_ * 4;

  dim3 gp(QPAD / 4, B_);
  dim3 gg(Q_ / 4, B_);

  const size_t need_A = 512 + 3 * (size_t)B_ * Q_ * 4 + (size_t)B_ * QPAD * 4 +
                        (size_t)B_ * Q_ * WPR * 8 + (size_t)B_ * QPAD * C_ * 2;
  const size_t need_B = 512 + (size_t)B_ * Q_ * 4 + (size_t)B_ * QPAD * 4 +
                        (size_t)B_ * Q_ * WPR * 8;

  if (ws_size >= need_A) {
    int* best_idx  = (int*)w;   w += B_ * Q_ * 4;
    float* best_sc = (float*)w; w += B_ * Q_ * 4;
    u32* rowmin = (u32*)w;      w += (size_t)B_ * QPAD * 4;
    u64* adj    = (u64*)w;      w += (size_t)B_ * Q_ * WPR * 8;
    unsigned short* nsig = (unsigned short*)w;

    k_compact<<<B_, 256, 0, stream>>>(logits, sel_idx, sel_cnt, dirty);
    k_prepg<<<gp, 256, 0, stream>>>(sig, logits, sel_idx, sel_cnt, nsig, rowmin,
                                    out, out_mask, out_scores);
    k_sim<<<B_ * NTRI, 256, 0, stream>>>(nsig, sel_cnt, adj, rowmin, dirty);
    k_fix<<<B_, 1024, 0, stream>>>(sig, logits, sel_idx, sel_cnt, adj, rowmin,
                                   dirty, best_idx, best_sc,
                                   out, out_mask, out_scores);
  } else if (ws_size >= need_B) {
    u32* rowmin = (u32*)w;  w += (size_t)B_ * QPAD * 4;
    u64* adj    = (u64*)w;
    unsigned short* nsig = (unsigned short*)((char*)d_out + (size_t)(8u << 20));

    k_compact<<<B_, 256, 0, stream>>>(logits, sel_idx, sel_cnt, dirty);
    k_prep<<<gp, 256, 0, stream>>>(sig, sel_idx, sel_cnt, nsig, rowmin);
    k_sim<<<B_ * NTRI, 256, 0, stream>>>(nsig, sel_cnt, adj, rowmin, dirty);
    k_ccgather<<<gg, 256, 0, stream>>>(sig, logits, sel_idx, sel_cnt, adj, rowmin,
                                       out, out_mask, out_scores);
  } else {
    u64* adj    = (u64*)d_out;
    u32* rowmin = (u32*)w;
    unsigned short* nsig = (unsigned short*)((char*)d_out + (size_t)(8u << 20));

    k_compact<<<B_, 256, 0, stream>>>(logits, sel_idx, sel_cnt, dirty);
    k_prep<<<gp, 256, 0, stream>>>(sig, sel_idx, sel_cnt, nsig, rowmin);
    k_sim<<<B_ * NTRI, 256, 0, stream>>>(nsig, sel_cnt, adj, rowmin, dirty);
    k_ccgather<<<gg, 256, 0, stream>>>(sig, logits, sel_idx, sel_cnt, adj, rowmin,
                                       out, out_mask, out_scores);
  }
}